// Round 2
// baseline (996.698 us; speedup 1.0000x reference)
//
#include <hip/hip_runtime.h>

// B=16, H=W=56, C=512, heads=8, hd=64; idx=0 -> H_sp=56, W_sp=7 -> S=392,
// 8 windows/batch, 128 windows total.  I/O dtype: float32 (per reference).
#define B_    16
#define HIMG  56
#define WIMG  56
#define L_    3136
#define C_    512
#define NH_   8
#define HD_   64
#define S_    392
#define TCH   64
#define NCH   7
#define QPASS 7

typedef short short4v __attribute__((ext_vector_type(4)));
typedef short short8  __attribute__((ext_vector_type(8)));
typedef float f32x4   __attribute__((ext_vector_type(4)));

__device__ __forceinline__ short f2bf(float f) {
    union { float f; unsigned int i; } x; x.f = f;
    unsigned int i = x.i;
    i += 0x7fffu + ((i >> 16) & 1u);   // RNE
    return (short)(i >> 16);
}
// window-position s (= h*7 + wsp) -> flat image index l for window column ww
__device__ __forceinline__ int l_of(int s, int ww) {
    int h = s / 7;
    int wp = s - h * 7;
    return h * WIMG + ww * 7 + wp;
}

// ---------------------------------------------------------------------------
// Kernel 1: depthwise 3x3 LePE conv (zero pad at window boundaries), fp32.
// Writes lepe (+bias) into d_out.  float4-coalesced.
// ---------------------------------------------------------------------------
__global__ __launch_bounds__(256) void lepe_kernel(
    const float* __restrict__ vp, const float* __restrict__ cw,
    const float* __restrict__ cb, float* __restrict__ out)
{
    int g    = blockIdx.x * 256 + threadIdx.x;   // (b*L + l)*128 + cgroup
    int c0   = (g & 127) * 4;
    int rest = g >> 7;                           // b*L + l
    int l    = rest % L_;
    int h    = l / WIMG;
    int wim  = l - h * WIMG;
    int wsp  = wim % 7;

    float wf[36];
#pragma unroll
    for (int i = 0; i < 4; ++i)
#pragma unroll
        for (int k = 0; k < 9; ++k)
            wf[i * 9 + k] = cw[(c0 + i) * 9 + k];

    float acc[4];
#pragma unroll
    for (int i = 0; i < 4; ++i) acc[i] = cb[c0 + i];

    const long long base = (long long)rest * C_ + c0;
#pragma unroll
    for (int dh = -1; dh <= 1; ++dh) {
        int hh = h + dh;
        if (hh < 0 || hh >= HIMG) continue;       // image edge == window edge (H_sp=56)
#pragma unroll
        for (int dw = -1; dw <= 1; ++dw) {
            int wp2 = wsp + dw;                   // zero-pad at WINDOW edge in w
            if (wp2 < 0 || wp2 >= 7) continue;
            f32x4 vv = *(const f32x4*)(vp + base + (long long)(dh * WIMG + dw) * C_);
            int k = (dh + 1) * 3 + (dw + 1);
#pragma unroll
            for (int i = 0; i < 4; ++i) acc[i] += vv[i] * wf[i * 9 + k];
        }
    }
    f32x4 o;
#pragma unroll
    for (int i = 0; i < 4; ++i) o[i] = acc[i];
    *(f32x4*)(out + base) = o;
}

// ---------------------------------------------------------------------------
// Kernel 2: flash-style window attention, one WG (4 waves) per (win, head).
// fp32 global I/O; bf16 MFMA internally; fp32 softmax state & O accumulate.
// LDS map (27 KB): [0,9216) sK bf16[64][72]; [9216,18432) sV bf16[64][72]
// (t-swizzled); [18432,27648) per-wave P bf16[16][72].  Epilogue aliases
// fp32 O[16][68] per wave over the sK/sV region (barrier-guarded).
// ---------------------------------------------------------------------------
__global__ __launch_bounds__(256) void attn_kernel(
    const float* __restrict__ qkv, float* __restrict__ out)
{
    const int head = blockIdx.x;          // 0..7
    const int win  = blockIdx.y;          // 0..127
    const int b    = win >> 3;
    const int ww   = win & 7;

    const int tid  = threadIdx.x;
    const int wave = tid >> 6;
    const int lane = tid & 63;
    const int ln   = lane & 15;
    const int quad = lane >> 4;

    const float* kp = qkv + (long long)B_ * L_ * C_;
    const float* vp = qkv + 2LL * (long long)B_ * L_ * C_;

    __shared__ __align__(16) char sMem[27648];
    short* sK = (short*)sMem;                                  // [64][72]
    short* sV = (short*)(sMem + 9216);                         // [64][72], t-swizzled
    short* sP = (short*)(sMem + 18432 + wave * 2304);          // [16][72]
    float* sO = (float*)(sMem + wave * 4608);                  // [16][68] epilogue only

    const int st_r = tid >> 4;         // 0..15 (row per staging round)
    const int st_c = (tid & 15) * 4;   // 0..60 (float4 column)

    const float SCL = 0.125f * 1.44269504088896340736f;  // hd^-0.5 * log2(e)

    for (int qb = 0; qb < QPASS; ++qb) {
        const int qrow0 = qb * 64 + wave * 16;
        int qs = qrow0 + ln; if (qs > S_ - 1) qs = S_ - 1;    // clamp tail rows
        const long long qoff = ((long long)b * L_ + l_of(qs, ww)) * C_ + head * HD_ + quad * 8;
        short8 aq0, aq1;   // A-frag: A[m=ln][k=quad*8+j], k 0..31 / 32..63
        {
            f32x4 x0 = *(const f32x4*)(qkv + qoff);
            f32x4 x1 = *(const f32x4*)(qkv + qoff + 4);
            f32x4 x2 = *(const f32x4*)(qkv + qoff + 32);
            f32x4 x3 = *(const f32x4*)(qkv + qoff + 36);
#pragma unroll
            for (int j = 0; j < 4; ++j) {
                aq0[j] = f2bf(x0[j]); aq0[4 + j] = f2bf(x1[j]);
                aq1[j] = f2bf(x2[j]); aq1[4 + j] = f2bf(x3[j]);
            }
        }

        f32x4 Oa[4];
        float mrun[4], lrun[4];
#pragma unroll
        for (int dt = 0; dt < 4; ++dt) { Oa[dt][0]=0.f; Oa[dt][1]=0.f; Oa[dt][2]=0.f; Oa[dt][3]=0.f; }
#pragma unroll
        for (int r = 0; r < 4; ++r) { mrun[r] = -1e30f; lrun[r] = 0.f; }

        for (int ch = 0; ch < NCH; ++ch) {
            const int t0 = ch * TCH;
            __syncthreads();   // prior reads of sK/sV (and epilogue sO) done
            // ---- stage K chunk: bf16, t-major ----
#pragma unroll
            for (int p = 0; p < 4; ++p) {
                int tl = p * 16 + st_r;
                int t  = t0 + tl;
                f32x4 kv = {0.f, 0.f, 0.f, 0.f};
                if (t < S_)
                    kv = *(const f32x4*)(kp + ((long long)b * L_ + l_of(t, ww)) * C_ + head * HD_ + st_c);
                short4v ks;
#pragma unroll
                for (int j = 0; j < 4; ++j) ks[j] = f2bf(kv[j]);
                *(short4v*)&sK[tl * 72 + st_c] = ks;
            }
            // ---- stage V chunk: bf16, d-major, t bits3..5 XOR-swizzled ----
#pragma unroll
            for (int p = 0; p < 4; ++p) {
                int tl = p * 16 + st_r;
                int t  = t0 + tl;
                f32x4 vv = {0.f, 0.f, 0.f, 0.f};
                if (t < S_)
                    vv = *(const f32x4*)(vp + ((long long)b * L_ + l_of(t, ww)) * C_ + head * HD_ + st_c);
#pragma unroll
                for (int j = 0; j < 4; ++j) {
                    int d   = st_c + j;
                    int tsw = tl ^ (((d >> 3) & 7) << 3);
                    sV[d * 72 + tsw] = f2bf(vv[j]);
                }
            }
            __syncthreads();

            // ---- S = Q K^T (16 q-rows x 64 keys per wave) ----
            f32x4 sc[4];
#pragma unroll
            for (int nt = 0; nt < 4; ++nt) {
                f32x4 acc = {0.f, 0.f, 0.f, 0.f};
                short8 bk0 = *(const short8*)&sK[(nt * 16 + ln) * 72 + quad * 8];
                short8 bk1 = *(const short8*)&sK[(nt * 16 + ln) * 72 + 32 + quad * 8];
                acc = __builtin_amdgcn_mfma_f32_16x16x32_bf16(aq0, bk0, acc, 0, 0, 0);
                acc = __builtin_amdgcn_mfma_f32_16x16x32_bf16(aq1, bk1, acc, 0, 0, 0);
                sc[nt] = acc;
            }
#pragma unroll
            for (int nt = 0; nt < 4; ++nt) {
                int t = t0 + nt * 16 + ln;
#pragma unroll
                for (int r = 0; r < 4; ++r) {
                    float v = sc[nt][r] * SCL;
                    sc[nt][r] = (t < S_) ? v : -1e30f;
                }
            }
            // ---- online softmax (base-2); P -> per-wave LDS in bf16 ----
#pragma unroll
            for (int r = 0; r < 4; ++r) {
                float mx = fmaxf(fmaxf(sc[0][r], sc[1][r]), fmaxf(sc[2][r], sc[3][r]));
                mx = fmaxf(mx, __shfl_xor(mx, 1));
                mx = fmaxf(mx, __shfl_xor(mx, 2));
                mx = fmaxf(mx, __shfl_xor(mx, 4));
                mx = fmaxf(mx, __shfl_xor(mx, 8));
                float mnew  = fmaxf(mrun[r], mx);
                float alpha = exp2f(mrun[r] - mnew);
                float p0 = exp2f(sc[0][r] - mnew);
                float p1 = exp2f(sc[1][r] - mnew);
                float p2 = exp2f(sc[2][r] - mnew);
                float p3 = exp2f(sc[3][r] - mnew);
                float rs = (p0 + p1) + (p2 + p3);
                rs += __shfl_xor(rs, 1);
                rs += __shfl_xor(rs, 2);
                rs += __shfl_xor(rs, 4);
                rs += __shfl_xor(rs, 8);
                lrun[r] = lrun[r] * alpha + rs;
                mrun[r] = mnew;
#pragma unroll
                for (int dt = 0; dt < 4; ++dt) Oa[dt][r] *= alpha;
                int row = quad * 4 + r;
                sP[row * 72 +  0 + ln] = f2bf(p0);
                sP[row * 72 + 16 + ln] = f2bf(p1);
                sP[row * 72 + 32 + ln] = f2bf(p2);
                sP[row * 72 + 48 + ln] = f2bf(p3);
            }
            // ---- O += P V ----
#pragma unroll
            for (int kc = 0; kc < 2; ++kc) {
                short8 ap = *(const short8*)&sP[ln * 72 + kc * 32 + quad * 8];
#pragma unroll
                for (int dt = 0; dt < 4; ++dt) {
                    int d     = dt * 16 + ln;
                    int colsw = (kc * 32 + quad * 8) ^ (((d >> 3) & 7) << 3);
                    short8 bv = *(const short8*)&sV[d * 72 + colsw];
                    Oa[dt] = __builtin_amdgcn_mfma_f32_16x16x32_bf16(ap, bv, Oa[dt], 0, 0, 0);
                }
            }
        } // chunk loop

        // ---- epilogue: normalize, fp32 transpose via sO (aliases sK/sV) ----
        __syncthreads();   // all waves done reading sK/sV for this qb
        float inv[4];
#pragma unroll
        for (int r = 0; r < 4; ++r) inv[r] = 1.0f / lrun[r];
#pragma unroll
        for (int dt = 0; dt < 4; ++dt)
#pragma unroll
            for (int r = 0; r < 4; ++r)
                sO[(quad * 4 + r) * 68 + dt * 16 + ln] = Oa[dt][r] * inv[r];
        // wave-local write->read: LDS ops per wave are in-order
#pragma unroll
        for (int p = 0; p < 4; ++p) {
            int rl   = p * 4 + (lane >> 4);
            int srow = qrow0 + rl;
            if (srow < S_) {
                int c0e = (lane & 15) * 4;
                f32x4 ov = *(const f32x4*)&sO[rl * 68 + c0e];
                long long off = ((long long)b * L_ + l_of(srow, ww)) * C_ + head * HD_ + c0e;
                f32x4 cur = *(const f32x4*)(out + off);   // lepe from kernel 1
                f32x4 res;
#pragma unroll
                for (int j = 0; j < 4; ++j) res[j] = ov[j] + cur[j];
                *(f32x4*)(out + off) = res;
            }
        }
    } // qb loop
}

extern "C" void kernel_launch(void* const* d_in, const int* in_sizes, int n_in,
                              void* d_out, int out_size, void* d_ws, size_t ws_size,
                              hipStream_t stream) {
    (void)in_sizes; (void)n_in; (void)d_ws; (void)ws_size; (void)out_size;
    const float* qkv = (const float*)d_in[0];
    const float* cw  = (const float*)d_in[1];
    const float* cb  = (const float*)d_in[2];
    float* out = (float*)d_out;
    const float* vp = qkv + 2LL * (long long)B_ * L_ * C_;

    // lepe writes d_out; attention RMW-adds onto it (same stream => ordered).
    lepe_kernel<<<dim3((B_ * L_ * (C_ / 4)) / 256), dim3(256), 0, stream>>>(vp, cw, cb, out);
    attn_kernel<<<dim3(NH_, B_ * 8), dim3(256), 0, stream>>>(qkv, out);
}

// Round 3
// 669.462 us; speedup vs baseline: 1.4888x; 1.4888x over previous
//
#include <hip/hip_runtime.h>

// B=16, H=W=56, C=512, heads=8, hd=64; idx=0 -> H_sp=56, W_sp=7 -> S=392,
// 8 windows/batch, 128 windows total.  I/O dtype: float32.
#define B_    16
#define HIMG  56
#define WIMG  56
#define L_    3136
#define C_    512
#define NH_   8
#define HD_   64
#define S_    392
#define NCH   7        // chunks of 64 keys
#define NQT   25       // ceil(392/16) q-tiles of 16 rows

typedef short short4v __attribute__((ext_vector_type(4)));
typedef short short8  __attribute__((ext_vector_type(8)));
typedef float f32x4   __attribute__((ext_vector_type(4)));

__device__ __forceinline__ short f2bf(float f) {
    union { float f; unsigned int i; } x; x.f = f;
    unsigned int i = x.i;
    i += 0x7fffu + ((i >> 16) & 1u);   // RNE
    return (short)(i >> 16);
}
// window-position s (= h*7 + wsp) -> flat image index l for window column ww
__device__ __forceinline__ int l_of(int s, int ww) {
    int h = s / 7;
    int wp = s - h * 7;
    return h * WIMG + ww * 7 + wp;
}

// ---------------------------------------------------------------------------
// Kernel 1: depthwise 3x3 LePE conv (zero pad at window boundaries), fp32.
// Weights staged in LDS (transposed [k][c], stride 516 for aligned float4).
// ---------------------------------------------------------------------------
__global__ __launch_bounds__(256) void lepe_kernel(
    const float* __restrict__ vp, const float* __restrict__ cw,
    const float* __restrict__ cb, float* __restrict__ out)
{
    __shared__ __align__(16) float sW[9 * 516];   // sW[k][c], 18.6 KB

    // cooperative load of all 512*9 weights, coalesced float4
    for (int i = threadIdx.x; i < 1152; i += 256) {
        f32x4 v = *(const f32x4*)(cw + i * 4);
#pragma unroll
        for (int j = 0; j < 4; ++j) {
            int e = 4 * i + j;
            int c = e / 9;
            int k = e - 9 * c;
            sW[k * 516 + c] = v[j];
        }
    }
    __syncthreads();

    int g    = blockIdx.x * 256 + threadIdx.x;
    int c0   = (g & 127) * 4;
    int rest = g >> 7;                 // b*L + l
    int l    = rest % L_;
    int h    = l / WIMG;
    int wim  = l - h * WIMG;
    int wsp  = wim % 7;

    f32x4 acc = *(const f32x4*)(cb + c0);
    const long long base = (long long)rest * C_ + c0;
#pragma unroll
    for (int dh = -1; dh <= 1; ++dh) {
        int hh = h + dh;
        if (hh < 0 || hh >= HIMG) continue;          // image edge == window edge in h
#pragma unroll
        for (int dw = -1; dw <= 1; ++dw) {
            int wp2 = wsp + dw;                      // zero-pad at WINDOW edge in w
            if (wp2 < 0 || wp2 >= 7) continue;
            f32x4 vv = *(const f32x4*)(vp + base + (long long)(dh * WIMG + dw) * C_);
            int k = (dh + 1) * 3 + (dw + 1);
            f32x4 wv = *(const f32x4*)&sW[k * 516 + c0];
#pragma unroll
            for (int i = 0; i < 4; ++i) acc[i] += vv[i] * wv[i];
        }
    }
    *(f32x4*)(out + base) = acc;
}

// ---------------------------------------------------------------------------
// Kernel 2: window attention, one WG (8 waves, 512 thr) per (win, head).
// FULL K and V for the (win,head) staged into LDS ONCE (bf16), then each
// wave independently processes q-tiles (16 rows) with online softmax over
// 7 resident chunks of 64 keys.  One __syncthreads total.
// LDS map: sK bf16[392][72] @0 (56448 B); sV bf16[64][448] t-swizzled
// @56448 (57344 B); per-wave P bf16[16][72] @113792 (18432 B). 132 KB.
// ---------------------------------------------------------------------------
__global__ __launch_bounds__(512) void attn_kernel(
    const float* __restrict__ qkv, float* __restrict__ out)
{
    const int head = blockIdx.x;          // 0..7
    const int win  = blockIdx.y;          // 0..127
    const int b    = win >> 3;
    const int ww   = win & 7;

    const int tid  = threadIdx.x;
    const int wave = tid >> 6;
    const int lane = tid & 63;
    const int ln   = lane & 15;
    const int quad = lane >> 4;

    const float* kp = qkv + (long long)B_ * L_ * C_;
    const float* vp = qkv + 2LL * (long long)B_ * L_ * C_;

    __shared__ __align__(16) short sAll[66112];
    short* sK = sAll;                          // [392][72]
    short* sV = sAll + 28224;                  // [64][448], t bits3..5 XOR swizzle
    short* sP = sAll + 56896 + wave * 1152;    // [16][72] per wave

    const int st_r = tid >> 4;         // 0..31
    const int st_c = (tid & 15) * 4;   // 0..60

    const long long kvbase = (long long)b * L_ * C_ + head * HD_;

    // ---- stage K (t-major bf16), once ----
#pragma unroll
    for (int p = 0; p < 13; ++p) {
        int t = p * 32 + st_r;
        if (t < S_) {
            f32x4 kv = *(const f32x4*)(kp + kvbase + (long long)l_of(t, ww) * C_ + st_c);
            short4v ks;
#pragma unroll
            for (int j = 0; j < 4; ++j) ks[j] = f2bf(kv[j]);
            *(short4v*)&sK[t * 72 + st_c] = ks;
        }
    }
    // ---- stage V (d-major bf16, swizzled within 64-chunks), zero tail ----
#pragma unroll
    for (int p = 0; p < 14; ++p) {
        int t = p * 32 + st_r;                 // 0..447
        f32x4 vv = {0.f, 0.f, 0.f, 0.f};
        if (t < S_)
            vv = *(const f32x4*)(vp + kvbase + (long long)l_of(t, ww) * C_ + st_c);
        int tb = t & ~63, tl = t & 63;
#pragma unroll
        for (int j = 0; j < 4; ++j) {
            int d  = st_c + j;
            int sw = ((d >> 3) & 7) << 3;
            sV[d * 448 + tb + (tl ^ sw)] = f2bf(vv[j]);
        }
    }
    __syncthreads();   // the only barrier

    const float SCL = 0.125f * 1.44269504088896340736f;  // hd^-0.5 * log2(e)

    for (int qt = wave; qt < NQT; qt += 8) {
        const int qrow0 = qt * 16;
        int qs = qrow0 + ln; if (qs > S_ - 1) qs = S_ - 1;
        const long long qoff = (long long)b * L_ * C_ + (long long)l_of(qs, ww) * C_ + head * HD_ + quad * 8;
        short8 aq0, aq1;   // A[m=ln][k=quad*8+j]
        {
            f32x4 x0 = *(const f32x4*)(qkv + qoff);
            f32x4 x1 = *(const f32x4*)(qkv + qoff + 4);
            f32x4 x2 = *(const f32x4*)(qkv + qoff + 32);
            f32x4 x3 = *(const f32x4*)(qkv + qoff + 36);
#pragma unroll
            for (int j = 0; j < 4; ++j) {
                aq0[j] = f2bf(x0[j]); aq0[4 + j] = f2bf(x1[j]);
                aq1[j] = f2bf(x2[j]); aq1[4 + j] = f2bf(x3[j]);
            }
        }

        f32x4 Oa[4];
        float mrun[4], lrun[4];
#pragma unroll
        for (int dt = 0; dt < 4; ++dt) { Oa[dt][0]=0.f; Oa[dt][1]=0.f; Oa[dt][2]=0.f; Oa[dt][3]=0.f; }
#pragma unroll
        for (int r = 0; r < 4; ++r) { mrun[r] = -1e30f; lrun[r] = 0.f; }

        for (int ch = 0; ch < NCH; ++ch) {
            const int t0 = ch * 64;
            // ---- S = Q K^T (16 rows x 64 keys) ----
            f32x4 sc[4];
#pragma unroll
            for (int nt = 0; nt < 4; ++nt) {
                int row = t0 + nt * 16 + ln;
                if (row > S_ - 1) row = S_ - 1;          // clamp (masked below)
                f32x4 acc = {0.f, 0.f, 0.f, 0.f};
                short8 bk0 = *(const short8*)&sK[row * 72 + quad * 8];
                short8 bk1 = *(const short8*)&sK[row * 72 + 32 + quad * 8];
                acc = __builtin_amdgcn_mfma_f32_16x16x32_bf16(aq0, bk0, acc, 0, 0, 0);
                acc = __builtin_amdgcn_mfma_f32_16x16x32_bf16(aq1, bk1, acc, 0, 0, 0);
                sc[nt] = acc;
            }
#pragma unroll
            for (int nt = 0; nt < 4; ++nt) {
                int t = t0 + nt * 16 + ln;
#pragma unroll
                for (int r = 0; r < 4; ++r) {
                    float v = sc[nt][r] * SCL;
                    sc[nt][r] = (t < S_) ? v : -1e30f;
                }
            }
            // ---- online softmax (base-2); P -> per-wave LDS bf16 ----
#pragma unroll
            for (int r = 0; r < 4; ++r) {
                float mx = fmaxf(fmaxf(sc[0][r], sc[1][r]), fmaxf(sc[2][r], sc[3][r]));
                mx = fmaxf(mx, __shfl_xor(mx, 1));
                mx = fmaxf(mx, __shfl_xor(mx, 2));
                mx = fmaxf(mx, __shfl_xor(mx, 4));
                mx = fmaxf(mx, __shfl_xor(mx, 8));
                float mnew  = fmaxf(mrun[r], mx);
                float alpha = exp2f(mrun[r] - mnew);
                float p0 = exp2f(sc[0][r] - mnew);
                float p1 = exp2f(sc[1][r] - mnew);
                float p2 = exp2f(sc[2][r] - mnew);
                float p3 = exp2f(sc[3][r] - mnew);
                float rs = (p0 + p1) + (p2 + p3);
                rs += __shfl_xor(rs, 1);
                rs += __shfl_xor(rs, 2);
                rs += __shfl_xor(rs, 4);
                rs += __shfl_xor(rs, 8);
                lrun[r] = lrun[r] * alpha + rs;
                mrun[r] = mnew;
#pragma unroll
                for (int dt = 0; dt < 4; ++dt) Oa[dt][r] *= alpha;
                int row = quad * 4 + r;
                sP[row * 72 +  0 + ln] = f2bf(p0);
                sP[row * 72 + 16 + ln] = f2bf(p1);
                sP[row * 72 + 32 + ln] = f2bf(p2);
                sP[row * 72 + 48 + ln] = f2bf(p3);
            }
            // ---- O += P V (bv via swizzled resident sV) ----
#pragma unroll
            for (int kc = 0; kc < 2; ++kc) {
                short8 ap = *(const short8*)&sP[ln * 72 + kc * 32 + quad * 8];
#pragma unroll
                for (int dt = 0; dt < 4; ++dt) {
                    int d     = dt * 16 + ln;
                    int colsw = (kc * 32 + quad * 8) ^ (((d >> 3) & 7) << 3);
                    short8 bv = *(const short8*)&sV[d * 448 + t0 + colsw];
                    Oa[dt] = __builtin_amdgcn_mfma_f32_16x16x32_bf16(ap, bv, Oa[dt], 0, 0, 0);
                }
            }
        } // chunk loop

        // ---- epilogue: fp32 RMW-add onto lepe, direct from C-layout ----
        float inv[4];
#pragma unroll
        for (int r = 0; r < 4; ++r) inv[r] = 1.0f / lrun[r];
#pragma unroll
        for (int r = 0; r < 4; ++r) {
            int row = qrow0 + quad * 4 + r;
            if (row < S_) {
                float* op = out + (long long)b * L_ * C_ + (long long)l_of(row, ww) * C_ + head * HD_ + ln;
#pragma unroll
                for (int dt = 0; dt < 4; ++dt)
                    op[dt * 16] += Oa[dt][r] * inv[r];
            }
        }
    } // q-tile loop
}

extern "C" void kernel_launch(void* const* d_in, const int* in_sizes, int n_in,
                              void* d_out, int out_size, void* d_ws, size_t ws_size,
                              hipStream_t stream) {
    (void)in_sizes; (void)n_in; (void)d_ws; (void)ws_size; (void)out_size;
    const float* qkv = (const float*)d_in[0];
    const float* cw  = (const float*)d_in[1];
    const float* cb  = (const float*)d_in[2];
    float* out = (float*)d_out;
    const float* vp = qkv + 2LL * (long long)B_ * L_ * C_;

    // lepe writes d_out; attention RMW-adds onto it (same stream => ordered).
    lepe_kernel<<<dim3((B_ * L_ * (C_ / 4)) / 256), dim3(256), 0, stream>>>(vp, cw, cb, out);
    attn_kernel<<<dim3(NH_, B_ * 8), dim3(512), 0, stream>>>(qkv, out);
}